// Round 2
// baseline (2230.258 us; speedup 1.0000x reference)
//
#include <hip/hip_runtime.h>
#include <stdint.h>

#define WSZ 8
#define MD 8192
#define ND 8192
#define KD 8192   // combined K = 8 * 1024
#define LK 1024

typedef __attribute__((ext_vector_type(8))) short short8;
typedef __attribute__((ext_vector_type(4))) float f32x4;
typedef __attribute__((ext_vector_type(8))) unsigned short u16x8;

__device__ __forceinline__ unsigned short f2bf(float f) {
  unsigned int u = __float_as_uint(f);
  u += 0x7fffu + ((u >> 16) & 1u);   // round-to-nearest-even
  return (unsigned short)(u >> 16);
}

// ---- A convert: x[r][m][k] f32 -> A[m][r*1024+k] bf16 (permute-cast, coalesced both sides)
__global__ __launch_bounds__(256) void conv_a(const float* __restrict__ x,
                                              unsigned short* __restrict__ A) {
  const size_t total8 = (size_t)WSZ * MD * LK / 8;   // 8,388,608 work items of 8 elems
  size_t stride = (size_t)gridDim.x * blockDim.x;
  for (size_t idx = (size_t)blockIdx.x * blockDim.x + threadIdx.x; idx < total8; idx += stride) {
    size_t e = idx * 8;
    unsigned int r   = (unsigned int)(e >> 23);            // / (8192*1024)
    unsigned int rem = (unsigned int)(e & ((1u << 23) - 1u));
    unsigned int m   = rem >> 10;
    unsigned int k   = rem & 1023u;
    const f32x4* src = (const f32x4*)(x + e);
    f32x4 v0 = src[0], v1 = src[1];
    u16x8 o;
    o[0] = f2bf(v0[0]); o[1] = f2bf(v0[1]); o[2] = f2bf(v0[2]); o[3] = f2bf(v0[3]);
    o[4] = f2bf(v1[0]); o[5] = f2bf(v1[1]); o[6] = f2bf(v1[2]); o[7] = f2bf(v1[3]);
    *(u16x8*)(A + (size_t)m * KD + r * LK + k) = o;
  }
}

// ---- B convert+transpose: W flat [kk][n] f32 -> Bt[n][kk] bf16, tiled via LDS
__global__ __launch_bounds__(256) void conv_bt(const float* __restrict__ w,
                                               unsigned short* __restrict__ Bt) {
  __shared__ float tile[64][65];
  const int nt = ND / 64;            // 128 n-tiles
  int bx = blockIdx.x % nt;          // n tile
  int by = blockIdx.x / nt;          // k tile
  int t = threadIdx.x;
  size_t kb = (size_t)by * 64, nb = (size_t)bx * 64;
  {
    int j  = t & 63;                 // n offset (coalesced read)
    int i0 = t >> 6;                 // 0..3
#pragma unroll
    for (int rep = 0; rep < 16; ++rep) {
      int i = i0 * 16 + rep;         // k offset
      tile[i][j] = w[(kb + i) * (size_t)ND + nb + j];
    }
  }
  __syncthreads();
  {
    int j2 = (t & 31) * 2;           // k offset pair (coalesced 4B write)
    int n0 = t >> 5;                 // 0..7
#pragma unroll
    for (int rep = 0; rep < 8; ++rep) {
      int n = n0 * 8 + rep;
      unsigned int pair = (unsigned int)f2bf(tile[j2][n]) |
                          ((unsigned int)f2bf(tile[j2 + 1][n]) << 16);
      *(unsigned int*)(Bt + (nb + n) * (size_t)KD + kb + j2) = pair;
    }
  }
}

// ---- bf16 GEMM, m97 structure: 128x128 tile, BK=32, 4 waves, 4x4 16x16x32 frags
#define BM 128
#define BN 128
#define BK 32

__global__ __launch_bounds__(256) void gemm_bf16(const unsigned short* __restrict__ A,
                                                 const unsigned short* __restrict__ Bt,
                                                 float* __restrict__ C) {
  __shared__ __align__(16) short As[BM * BK];  // [128][32] linear (global_load_lds dest)
  __shared__ __align__(16) short Bs[BN * BK];  // [128][32] linear (Bt rows = n)
  int t = threadIdx.x;
  int lane = t & 63;
  int wid  = t >> 6;

  // XCD-bijective swizzle (nwg=4096, %8==0) + GROUP_M=8 supertiles
  const int nwg = 64 * 64;
  const int cpx = nwg >> 3;
  int orig = blockIdx.x;
  int wg = (orig & 7) * cpx + (orig >> 3);
  const int GM = 8;
  const int width = GM * 64;
  int group = wg / width;
  int pid_m = group * GM + (wg % GM);
  int pid_n = (wg % width) / GM;

  size_t arow = (size_t)pid_m * BM;
  size_t brow = (size_t)pid_n * BN;

  // staging source: lane t covers row t/4, col-bytes (t&3)*16 of the [128][32] tile
  const unsigned short* ga = A  + (arow + (size_t)(t >> 2)) * KD + (size_t)(t & 3) * 8;
  const unsigned short* gb = Bt + (brow + (size_t)(t >> 2)) * KD + (size_t)(t & 3) * 8;

  int wm = wid >> 1, wn = wid & 1;
  int lr = lane & 15;    // A-row / B-col within fragment
  int kg = lane >> 4;    // k-group (8 consecutive k per lane)

  const short* pa0 = &As[(wm * 64 + lr) * BK + kg * 8];
  const short* pb0 = &Bs[(wn * 64 + lr) * BK + kg * 8];

  f32x4 acc[4][4];
#pragma unroll
  for (int i = 0; i < 4; ++i)
#pragma unroll
    for (int j = 0; j < 4; ++j)
      acc[i][j] = (f32x4){0.f, 0.f, 0.f, 0.f};

  for (int kt = 0; kt < KD / BK; ++kt) {
    const unsigned short* gak = ga + kt * BK;
    const unsigned short* gbk = gb + kt * BK;
    __builtin_amdgcn_global_load_lds(
        (const __attribute__((address_space(1))) unsigned int*)gak,
        (__attribute__((address_space(3))) unsigned int*)&As[t * 8], 16, 0, 0);
    __builtin_amdgcn_global_load_lds(
        (const __attribute__((address_space(1))) unsigned int*)(gak + (size_t)64 * KD),
        (__attribute__((address_space(3))) unsigned int*)&As[2048 + t * 8], 16, 0, 0);
    __builtin_amdgcn_global_load_lds(
        (const __attribute__((address_space(1))) unsigned int*)gbk,
        (__attribute__((address_space(3))) unsigned int*)&Bs[t * 8], 16, 0, 0);
    __builtin_amdgcn_global_load_lds(
        (const __attribute__((address_space(1))) unsigned int*)(gbk + (size_t)64 * KD),
        (__attribute__((address_space(3))) unsigned int*)&Bs[2048 + t * 8], 16, 0, 0);
    __syncthreads();   // compiler emits vmcnt(0) drain before s_barrier

    short8 af[4], bfr[4];
#pragma unroll
    for (int mi = 0; mi < 4; ++mi) af[mi]  = *(const short8*)(pa0 + mi * 16 * BK);
#pragma unroll
    for (int ni = 0; ni < 4; ++ni) bfr[ni] = *(const short8*)(pb0 + ni * 16 * BK);
#pragma unroll
    for (int mi = 0; mi < 4; ++mi)
#pragma unroll
      for (int ni = 0; ni < 4; ++ni)
        acc[mi][ni] = __builtin_amdgcn_mfma_f32_16x16x32_bf16(af[mi], bfr[ni], acc[mi][ni], 0, 0, 0);
    __syncthreads();
  }

  // epilogue: C/D layout col=lane&15, row=(lane>>4)*4+reg  [m89-verified]
  size_t crow = arow + (size_t)(wm * 64 + kg * 4);
  size_t ccol = brow + (size_t)(wn * 64 + lr);
#pragma unroll
  for (int mi = 0; mi < 4; ++mi) {
#pragma unroll
    for (int ni = 0; ni < 4; ++ni) {
      f32x4 v = acc[mi][ni];
#pragma unroll
      for (int j = 0; j < 4; ++j)
        C[(crow + mi * 16 + j) * ND + ccol + ni * 16] = v[j];
    }
  }
}

extern "C" void kernel_launch(void* const* d_in, const int* in_sizes, int n_in,
                              void* d_out, int out_size, void* d_ws, size_t ws_size,
                              hipStream_t stream) {
  const float* x = (const float*)d_in[0];
  const float* w = (const float*)d_in[1];
  float* out = (float*)d_out;

  unsigned short* Abf = (unsigned short*)d_ws;                  // 8192*8192 bf16 = 134 MB
  unsigned short* Bbf = Abf + (size_t)MD * KD;                  // next 134 MB

  conv_a<<<4096, 256, 0, stream>>>(x, Abf);
  conv_bt<<<(KD / 64) * (ND / 64), 256, 0, stream>>>(w, Bbf);
  gemm_bf16<<<64 * 64, 256, 0, stream>>>(Abf, Bbf, out);
}

// Round 5
// 1999.308 us; speedup vs baseline: 1.1155x; 1.1155x over previous
//
#include <hip/hip_runtime.h>
#include <stdint.h>

#define WSZ 8
#define MD 8192
#define ND 8192
#define KD 8192
#define LK 1024

typedef __attribute__((ext_vector_type(8))) short short8;
typedef __attribute__((ext_vector_type(4))) float f32x4;
typedef __attribute__((ext_vector_type(8))) unsigned short u16x8;

__device__ __forceinline__ unsigned short f2bf(float f) {
  unsigned int u = __float_as_uint(f);
  u += 0x7fffu + ((u >> 16) & 1u);
  return (unsigned short)(u >> 16);
}

// ---- A convert: x[r][m][k] f32 -> A[m][r*1024+k] bf16
__global__ __launch_bounds__(256) void conv_a(const float* __restrict__ x,
                                              unsigned short* __restrict__ A) {
  const size_t total8 = (size_t)WSZ * MD * LK / 8;
  size_t stride = (size_t)gridDim.x * blockDim.x;
  for (size_t idx = (size_t)blockIdx.x * blockDim.x + threadIdx.x; idx < total8; idx += stride) {
    size_t e = idx * 8;
    unsigned int r   = (unsigned int)(e >> 23);
    unsigned int rem = (unsigned int)(e & ((1u << 23) - 1u));
    unsigned int m   = rem >> 10;
    unsigned int k   = rem & 1023u;
    const f32x4* src = (const f32x4*)(x + e);
    f32x4 v0 = src[0], v1 = src[1];
    u16x8 o;
    o[0] = f2bf(v0[0]); o[1] = f2bf(v0[1]); o[2] = f2bf(v0[2]); o[3] = f2bf(v0[3]);
    o[4] = f2bf(v1[0]); o[5] = f2bf(v1[1]); o[6] = f2bf(v1[2]); o[7] = f2bf(v1[3]);
    *(u16x8*)(A + (size_t)m * KD + r * LK + k) = o;
  }
}

// ---- B convert+transpose: W[k][n] f32 -> Bt[n][k] bf16; 16B-granular writes
__global__ __launch_bounds__(256) void conv_bt(const float* __restrict__ w,
                                               unsigned short* __restrict__ Bt) {
  __shared__ float tile[64][65];
  const int nt = ND / 64;
  int bx = blockIdx.x % nt;          // n tile
  int by = blockIdx.x / nt;          // k tile
  int t = threadIdx.x;
  size_t kb = (size_t)by * 64, nb = (size_t)bx * 64;
  {
    int j  = t & 63;
    int i0 = t >> 6;
#pragma unroll
    for (int rep = 0; rep < 16; ++rep) {
      int i = i0 * 16 + rep;
      tile[i][j] = w[(kb + i) * (size_t)ND + nb + j];
    }
  }
  __syncthreads();
  {
    int n  = t >> 2;                 // 0..63
    int ks = t & 3;
#pragma unroll
    for (int rep = 0; rep < 2; ++rep) {
      int k8 = ks + rep * 4;         // 0..7, 8 consecutive k per write
      u16x8 o;
#pragma unroll
      for (int i = 0; i < 8; ++i) o[i] = f2bf(tile[k8 * 8 + i][n]);
      *(u16x8*)(Bt + (nb + n) * (size_t)KD + kb + k8 * 8) = o;
    }
  }
}

// ---- bf16 GEMM: 256x256 tile, BK=32, 8 waves (2Mx4N), 3-buffer LDS rotation,
//      counted vmcnt(4) boundary (T4), setprio around MFMA (T5), raw s_barrier.
#define BM 256
#define BN 256
#define BK 32
#define NT (KD / BK)   // 256 K-tiles

#define GLDS(src, dst)                                                           \
  __builtin_amdgcn_global_load_lds(                                              \
      (const __attribute__((address_space(1))) unsigned int*)(src),              \
      (__attribute__((address_space(3))) unsigned int*)(dst), 16, 0, 0)

__global__ __launch_bounds__(512, 1) void gemm_bf16(const unsigned short* __restrict__ A,
                                                    const unsigned short* __restrict__ Bt,
                                                    float* __restrict__ C) {
  // 3 buffers x (A 16KiB + B 16KiB) = 96 KiB
  __shared__ __align__(16) short As[3][BM * BK];
  __shared__ __align__(16) short Bs[3][BN * BK];

  int t = threadIdx.x;
  int lane = t & 63;
  int wid  = t >> 6;        // 0..7
  int wr = wid >> 2;        // 0..1  (M half)
  int wc = wid & 3;         // 0..3  (N quarter)
  int lr = lane & 15;
  int kg = lane >> 4;       // 0..3

  // XCD-bijective swizzle (nwg=1024, %8==0) + GROUP_M=8
  const int nwg = 32 * 32;
  int orig = blockIdx.x;
  int wg = (orig & 7) * (nwg >> 3) + (orig >> 3);
  const int GM = 8;
  const int width = GM * 32;
  int group = wg / width;
  int pid_m = group * GM + (wg % GM);
  int pid_n = (wg % width) / GM;

  size_t arow = (size_t)pid_m * BM;
  size_t brow = (size_t)pid_n * BN;

  // staging source bases: thread t covers row (t>>2) of a 128-row chunk, 16B slot (t&3)
  const unsigned short* pA = A  + (arow + (size_t)(t >> 2)) * KD + (size_t)(t & 3) * 8;
  const unsigned short* pB = Bt + (brow + (size_t)(t >> 2)) * KD + (size_t)(t & 3) * 8;

  // fragment read offsets (elements)
  const int aoff = (wr * 128 + lr) * BK + kg * 8;   // + mi*16*BK
  const int boff = (wc * 64 + lr) * BK + kg * 8;    // + ni*16*BK

  f32x4 acc[8][4];
#pragma unroll
  for (int i = 0; i < 8; ++i)
#pragma unroll
    for (int j = 0; j < 4; ++j) acc[i][j] = (f32x4){0.f, 0.f, 0.f, 0.f};

  // stage one K-tile (4 wave-loads: A chunks 0,1 / B chunks 0,1) into buffer b
  auto stage = [&](int kt, int b) {
    const unsigned short* sa = pA + (size_t)kt * BK;
    const unsigned short* sb = pB + (size_t)kt * BK;
    GLDS(sa,                    &As[b][t * 8]);
    GLDS(sa + (size_t)128 * KD, &As[b][4096 + t * 8]);
    GLDS(sb,                    &Bs[b][t * 8]);
    GLDS(sb + (size_t)128 * KD, &Bs[b][4096 + t * 8]);
  };

  // prologue: tiles 0,1 -> bufs 0,1 ; wait tile0 only (counted)
  stage(0, 0);
  stage(1, 1);
  asm volatile("s_waitcnt vmcnt(4)" ::: "memory");
  asm volatile("s_barrier" ::: "memory");

  int cur = 0;
  for (int kt = 0; kt < NT; ++kt) {
    int pre = cur + 2; if (pre >= 3) pre -= 3;
    if (kt + 2 < NT) stage(kt + 2, pre);   // overwrites tile kt-1's buffer: consumed last iter

    const short* Ac = &As[cur][0];
    const short* Bc = &Bs[cur][0];

    // phase 0: frags mi 0..3 x ni 0..3
    short8 af[4], bf[4];
#pragma unroll
    for (int mi = 0; mi < 4; ++mi) af[mi] = *(const short8*)(Ac + aoff + mi * 16 * BK);
#pragma unroll
    for (int ni = 0; ni < 4; ++ni) bf[ni] = *(const short8*)(Bc + boff + ni * 16 * BK);
    __builtin_amdgcn_s_setprio(1);
#pragma unroll
    for (int mi = 0; mi < 4; ++mi)
#pragma unroll
      for (int ni = 0; ni < 4; ++ni)
        acc[mi][ni] = __builtin_amdgcn_mfma_f32_16x16x32_bf16(af[mi], bf[ni], acc[mi][ni], 0, 0, 0);
    __builtin_amdgcn_s_setprio(0);

    // phase 1: frags mi 4..7 x ni 0..3 (reuse bf)
    short8 ag[4];
#pragma unroll
    for (int mi = 0; mi < 4; ++mi) ag[mi] = *(const short8*)(Ac + aoff + (4 + mi) * 16 * BK);
    __builtin_amdgcn_s_setprio(1);
#pragma unroll
    for (int mi = 0; mi < 4; ++mi)
#pragma unroll
      for (int ni = 0; ni < 4; ++ni)
        acc[4 + mi][ni] = __builtin_amdgcn_mfma_f32_16x16x32_bf16(ag[mi], bf[ni], acc[4 + mi][ni], 0, 0, 0);
    __builtin_amdgcn_s_setprio(0);

    // boundary: all my LDS reads done; next tile's 4 loads retired (counted, not 0)
    asm volatile("s_waitcnt lgkmcnt(0)" ::: "memory");
    if (kt < NT - 2) {
      asm volatile("s_waitcnt vmcnt(4)" ::: "memory");
    } else {
      asm volatile("s_waitcnt vmcnt(0)" ::: "memory");
    }
    asm volatile("s_barrier" ::: "memory");

    cur = cur + 1; if (cur >= 3) cur = 0;
  }

  // epilogue: C/D layout col=lane&15, row=(lane>>4)*4+reg (m89-verified, same as round 2)
  size_t crow = arow + (size_t)(wr * 128 + kg * 4);
  size_t ccol = brow + (size_t)(wc * 64 + lr);
#pragma unroll
  for (int mi = 0; mi < 8; ++mi) {
#pragma unroll
    for (int ni = 0; ni < 4; ++ni) {
      f32x4 v = acc[mi][ni];
#pragma unroll
      for (int j = 0; j < 4; ++j)
        C[(crow + mi * 16 + j) * ND + ccol + ni * 16] = v[j];
    }
  }
}

extern "C" void kernel_launch(void* const* d_in, const int* in_sizes, int n_in,
                              void* d_out, int out_size, void* d_ws, size_t ws_size,
                              hipStream_t stream) {
  const float* x = (const float*)d_in[0];
  const float* w = (const float*)d_in[1];
  float* out = (float*)d_out;

  unsigned short* Abf = (unsigned short*)d_ws;
  unsigned short* Bbf = Abf + (size_t)MD * KD;

  conv_a<<<4096, 256, 0, stream>>>(x, Abf);
  conv_bt<<<(KD / 64) * (ND / 64), 256, 0, stream>>>(w, Bbf);
  gemm_bf16<<<32 * 32, 512, 0, stream>>>(Abf, Bbf, out);
}

// Round 6
// 1988.021 us; speedup vs baseline: 1.1218x; 1.0057x over previous
//
#include <hip/hip_runtime.h>
#include <stdint.h>

#define WSZ 8
#define MD 8192
#define ND 8192
#define KD 8192
#define LK 1024

typedef __attribute__((ext_vector_type(8))) short short8;
typedef __attribute__((ext_vector_type(4))) float f32x4;
typedef __attribute__((ext_vector_type(8))) unsigned short u16x8;

__device__ __forceinline__ unsigned short f2bf(float f) {
  unsigned int u = __float_as_uint(f);
  u += 0x7fffu + ((u >> 16) & 1u);
  return (unsigned short)(u >> 16);
}

// ---- A convert: x[r][m][k] f32 -> A[m][r*1024+k] bf16
__global__ __launch_bounds__(256) void conv_a(const float* __restrict__ x,
                                              unsigned short* __restrict__ A) {
  const size_t total8 = (size_t)WSZ * MD * LK / 8;
  size_t stride = (size_t)gridDim.x * blockDim.x;
  for (size_t idx = (size_t)blockIdx.x * blockDim.x + threadIdx.x; idx < total8; idx += stride) {
    size_t e = idx * 8;
    unsigned int r   = (unsigned int)(e >> 23);
    unsigned int rem = (unsigned int)(e & ((1u << 23) - 1u));
    unsigned int m   = rem >> 10;
    unsigned int k   = rem & 1023u;
    const f32x4* src = (const f32x4*)(x + e);
    f32x4 v0 = src[0], v1 = src[1];
    u16x8 o;
    o[0] = f2bf(v0[0]); o[1] = f2bf(v0[1]); o[2] = f2bf(v0[2]); o[3] = f2bf(v0[3]);
    o[4] = f2bf(v1[0]); o[5] = f2bf(v1[1]); o[6] = f2bf(v1[2]); o[7] = f2bf(v1[3]);
    *(u16x8*)(A + (size_t)m * KD + r * LK + k) = o;
  }
}

// ---- B convert+transpose: W[k][n] f32 -> Bt[n][k] bf16; 128B-contiguous writes
__global__ __launch_bounds__(256) void conv_bt(const float* __restrict__ w,
                                               unsigned short* __restrict__ Bt) {
  __shared__ float tile[64][65];
  const int nt = ND / 64;
  int bx = blockIdx.x % nt;          // n tile
  int by = blockIdx.x / nt;          // k tile
  int t = threadIdx.x;
  size_t kb = (size_t)by * 64, nb = (size_t)bx * 64;
  {
    int j  = t & 63;
    int i0 = t >> 6;
#pragma unroll
    for (int rep = 0; rep < 16; ++rep) {
      int i = i0 * 16 + rep;
      tile[i][j] = w[(kb + i) * (size_t)ND + nb + j];
    }
  }
  __syncthreads();
  {
    int n0 = t >> 3;                 // 0..31
    int ks = t & 7;                  // 16B slot -> k = ks*8 .. ks*8+7
#pragma unroll
    for (int rep = 0; rep < 2; ++rep) {
      int n = n0 + rep * 32;
      u16x8 o;
#pragma unroll
      for (int i = 0; i < 8; ++i) o[i] = f2bf(tile[ks * 8 + i][n]);
      *(u16x8*)(Bt + (nb + n) * (size_t)KD + kb + ks * 8) = o;
    }
  }
}

// ---- bf16 GEMM: 256x256 tile, BK=32, 8 waves (2Mx4N), 3-buffer LDS rotation,
//      counted vmcnt(4) boundary (T4), setprio around MFMA (T5),
//      T2 XOR-swizzle on k-slots: LDS pos (row, s) holds k-slot s^(row&3).
//      (linear gload_lds dest + inverse-swizzled SOURCE + swizzled READ, rule #21)
#define BM 256
#define BN 256
#define BK 32
#define NT (KD / BK)   // 256 K-tiles

#define GLDS(src, dst)                                                           \
  __builtin_amdgcn_global_load_lds(                                              \
      (const __attribute__((address_space(1))) unsigned int*)(src),              \
      (__attribute__((address_space(3))) unsigned int*)(dst), 16, 0, 0)

__global__ __launch_bounds__(512, 1) void gemm_bf16(const unsigned short* __restrict__ A,
                                                    const unsigned short* __restrict__ Bt,
                                                    float* __restrict__ C) {
  __shared__ __align__(16) short As[3][BM * BK];
  __shared__ __align__(16) short Bs[3][BN * BK];

  int t = threadIdx.x;
  int lane = t & 63;
  int wid  = t >> 6;        // 0..7
  int wr = wid >> 2;        // 0..1  (M half)
  int wc = wid & 3;         // 0..3  (N quarter)
  int lr = lane & 15;
  int kg = lane >> 4;       // 0..3

  // XCD-bijective swizzle (nwg=1024, %8==0) + GROUP_M=8
  const int nwg = 32 * 32;
  int orig = blockIdx.x;
  int wg = (orig & 7) * (nwg >> 3) + (orig >> 3);
  const int GM = 8;
  const int width = GM * 32;
  int group = wg / width;
  int pid_m = group * GM + (wg % GM);
  int pid_n = (wg % width) / GM;

  size_t arow = (size_t)pid_m * BM;
  size_t brow = (size_t)pid_n * BN;

  // staging source: thread t covers row (t>>2), 16B slot swizzled by row:
  // slot_src = (t&3) ^ ((t>>2)&3)  [chunk1 at +128 rows: 128%4==0, same xor]
  int sslot = (t & 3) ^ ((t >> 2) & 3);
  const unsigned short* pA = A  + (arow + (size_t)(t >> 2)) * KD + (size_t)sslot * 8;
  const unsigned short* pB = Bt + (brow + (size_t)(t >> 2)) * KD + (size_t)sslot * 8;

  // fragment read offsets: swizzled k-slot = kg ^ (row&3); row&3 == lr&3 for all mi/ni
  const int kslot = (kg ^ (lr & 3)) * 8;
  const int aoff = (wr * 128 + lr) * BK + kslot;   // + mi*16*BK
  const int boff = (wc * 64 + lr) * BK + kslot;    // + ni*16*BK

  f32x4 acc[8][4];
#pragma unroll
  for (int i = 0; i < 8; ++i)
#pragma unroll
    for (int j = 0; j < 4; ++j) acc[i][j] = (f32x4){0.f, 0.f, 0.f, 0.f};

  auto stage = [&](int kt, int b) {
    const unsigned short* sa = pA + (size_t)kt * BK;
    const unsigned short* sb = pB + (size_t)kt * BK;
    GLDS(sa,                    &As[b][t * 8]);
    GLDS(sa + (size_t)128 * KD, &As[b][4096 + t * 8]);
    GLDS(sb,                    &Bs[b][t * 8]);
    GLDS(sb + (size_t)128 * KD, &Bs[b][4096 + t * 8]);
  };

  // prologue: tiles 0,1 -> bufs 0,1 ; wait tile0 only (counted)
  stage(0, 0);
  stage(1, 1);
  asm volatile("s_waitcnt vmcnt(4)" ::: "memory");
  asm volatile("s_barrier" ::: "memory");

  int cur = 0;
  for (int kt = 0; kt < NT; ++kt) {
    int pre = cur + 2; if (pre >= 3) pre -= 3;
    if (kt + 2 < NT) stage(kt + 2, pre);   // overwrites tile kt-1's buffer: consumed last iter

    const short* Ac = &As[cur][0];
    const short* Bc = &Bs[cur][0];

    // phase 0: frags mi 0..3 x ni 0..3
    short8 af[4], bf[4];
#pragma unroll
    for (int mi = 0; mi < 4; ++mi) af[mi] = *(const short8*)(Ac + aoff + mi * 16 * BK);
#pragma unroll
    for (int ni = 0; ni < 4; ++ni) bf[ni] = *(const short8*)(Bc + boff + ni * 16 * BK);
    __builtin_amdgcn_s_setprio(1);
#pragma unroll
    for (int mi = 0; mi < 4; ++mi)
#pragma unroll
      for (int ni = 0; ni < 4; ++ni)
        acc[mi][ni] = __builtin_amdgcn_mfma_f32_16x16x32_bf16(af[mi], bf[ni], acc[mi][ni], 0, 0, 0);
    __builtin_amdgcn_s_setprio(0);

    // phase 1: frags mi 4..7 x ni 0..3 (reuse bf)
    short8 ag[4];
#pragma unroll
    for (int mi = 0; mi < 4; ++mi) ag[mi] = *(const short8*)(Ac + aoff + (4 + mi) * 16 * BK);
    __builtin_amdgcn_s_setprio(1);
#pragma unroll
    for (int mi = 0; mi < 4; ++mi)
#pragma unroll
      for (int ni = 0; ni < 4; ++ni)
        acc[4 + mi][ni] = __builtin_amdgcn_mfma_f32_16x16x32_bf16(ag[mi], bf[ni], acc[4 + mi][ni], 0, 0, 0);
    __builtin_amdgcn_s_setprio(0);

    // boundary: all my LDS reads done; next tile's 4 loads retired (counted, not 0)
    asm volatile("s_waitcnt lgkmcnt(0)" ::: "memory");
    if (kt < NT - 2) {
      asm volatile("s_waitcnt vmcnt(4)" ::: "memory");
    } else {
      asm volatile("s_waitcnt vmcnt(0)" ::: "memory");
    }
    asm volatile("s_barrier" ::: "memory");

    cur = cur + 1; if (cur >= 3) cur = 0;
  }

  // epilogue: C/D layout col=lane&15, row=(lane>>4)*4+reg (m89-verified)
  size_t crow = arow + (size_t)(wr * 128 + kg * 4);
  size_t ccol = brow + (size_t)(wc * 64 + lr);
#pragma unroll
  for (int mi = 0; mi < 8; ++mi) {
#pragma unroll
    for (int ni = 0; ni < 4; ++ni) {
      f32x4 v = acc[mi][ni];
#pragma unroll
      for (int j = 0; j < 4; ++j)
        C[(crow + mi * 16 + j) * ND + ccol + ni * 16] = v[j];
    }
  }
}

extern "C" void kernel_launch(void* const* d_in, const int* in_sizes, int n_in,
                              void* d_out, int out_size, void* d_ws, size_t ws_size,
                              hipStream_t stream) {
  const float* x = (const float*)d_in[0];
  const float* w = (const float*)d_in[1];
  float* out = (float*)d_out;

  unsigned short* Abf = (unsigned short*)d_ws;
  unsigned short* Bbf = Abf + (size_t)MD * KD;

  conv_a<<<4096, 256, 0, stream>>>(x, Abf);
  conv_bt<<<(KD / 64) * (ND / 64), 256, 0, stream>>>(w, Bbf);
  gemm_bf16<<<32 * 32, 512, 0, stream>>>(Abf, Bbf, out);
}